// Round 1
// 1009.906 us; speedup vs baseline: 1.3895x; 1.3895x over previous
//
#include <hip/hip_runtime.h>
#include <math.h>

#define D 256
#define WDIM 128
#define EPSN 1e-10f
#define CHUNK 2048
#define C2 2048

typedef __attribute__((ext_vector_type(8))) short short8v;
typedef __attribute__((ext_vector_type(4))) float f32x4;

#define XPAD 264   // 256 + 8 bf16 pad -> row stride 528B = 33*16, banks spread
#define MPAD 136   // 128 + 8 bf16 pad -> row stride 272B = 17*16

// ---- fp32 -> bf16 hi/lo split (RNE both): dropped lo*lo term ~2^-18 rel ----
__device__ __forceinline__ unsigned short bf16_rne(float f) {
    unsigned u = __float_as_uint(f);
    u += 0x7fffu + ((u >> 16) & 1u);
    return (unsigned short)(u >> 16);
}
__device__ __forceinline__ float bf16_tof(unsigned short h) {
    return __uint_as_float(((unsigned)h) << 16);
}
__device__ __forceinline__ void split2(float f, unsigned short& h, unsigned short& l) {
    h = bf16_rne(f);
    l = bf16_rne(f - bf16_tof(h));
}

// ---------------- init: zero counters ----------------
__global__ void k_init(int* cnt) {
    if (threadIdx.x == 0) { cnt[0] = 0; cnt[1] = 0; ((float*)cnt)[2] = 0.0f; }
}

// ---------------- weight conversion: Wcat=[Wmu;Wlv] and Wdec -> bf16 hi/lo ----------------
__global__ __launch_bounds__(256) void k_wconv(const float* __restrict__ Wmu,
                                               const float* __restrict__ Wlv,
                                               const float* __restrict__ Wdec,
                                               unsigned short* __restrict__ wcat_h,
                                               unsigned short* __restrict__ wcat_l,
                                               unsigned short* __restrict__ wdec_h,
                                               unsigned short* __restrict__ wdec_l) {
    int i = blockIdx.x * 256 + threadIdx.x;
    if (i < 65536) {                       // 256 rows x 256 cols
        float v = (i < 32768) ? Wmu[i] : Wlv[i - 32768];
        unsigned short h, l; split2(v, h, l);
        wcat_h[i] = h; wcat_l[i] = l;
    } else if (i < 98304) {                // 256 rows x 128 cols
        int j = i - 65536;
        unsigned short h, l; split2(Wdec[j], h, l);
        wdec_h[j] = h; wdec_l[j] = l;
    }
}

// ---------------- copy x -> new_features, compute per-row inv-norm ----------------
__global__ __launch_bounds__(256) void k_copy_norm(const float* __restrict__ x,
                                                   float* __restrict__ outF,
                                                   float* __restrict__ rowinv, int N) {
    int wid = threadIdx.x >> 6, lane = threadIdx.x & 63;
    int row = blockIdx.x * 4 + wid;
    if (row >= N) return;
    float4 v = ((const float4*)(x + (size_t)row * D))[lane];
    ((float4*)(outF + (size_t)row * D))[lane] = v;
    float s = v.x * v.x + v.y * v.y + v.z * v.z + v.w * v.w;
    #pragma unroll
    for (int m = 32; m; m >>= 1) s += __shfl_xor(s, m, 64);
    if (lane == 0) rowinv[row] = 1.0f / (sqrtf(s) + EPSN);
}

// ---------------- classify tiers into compacted lists ----------------
__global__ __launch_bounds__(256) void k_classify(const int* __restrict__ tiers, int* cnt,
                                                  int* __restrict__ warm_idx,
                                                  int* __restrict__ cold_idx, int N) {
    int i = blockIdx.x * 256 + threadIdx.x;
    bool w = false, c = false;
    if (i < N) { int t = tiers[i]; w = (t == 1); c = (t == 2); }
    unsigned long long mw = __ballot(w);
    unsigned long long mc = __ballot(c);
    int lane = threadIdx.x & 63;
    unsigned long long ltmask = (lane == 0) ? 0ULL : (~0ULL >> (64 - lane));
    int pw = __popcll(mw & ltmask);
    int pc = __popcll(mc & ltmask);
    int cw = __popcll(mw), cc = __popcll(mc);
    int bw = 0, bc = 0;
    if (lane == 0) {
        if (cw) bw = atomicAdd(&cnt[0], cw);
        if (cc) bc = atomicAdd(&cnt[1], cc);
    }
    bw = __shfl(bw, 0, 64);
    bc = __shfl(bc, 0, 64);
    if (w) warm_idx[bw + pw] = i;
    if (c) cold_idx[bc + pc] = i;
}

// ---------------- normalize queries ----------------
__global__ __launch_bounds__(256) void k_qnorm(const float* __restrict__ q,
                                               float* __restrict__ qn, int B) {
    int wid = threadIdx.x >> 6, lane = threadIdx.x & 63;
    int row = blockIdx.x * 4 + wid;
    if (row >= B) return;
    float4 v = ((const float4*)(q + (size_t)row * D))[lane];
    float s = v.x * v.x + v.y * v.y + v.z * v.z + v.w * v.w;
    #pragma unroll
    for (int m = 32; m; m >>= 1) s += __shfl_xor(s, m, 64);
    float inv = 1.0f / (sqrtf(s) + EPSN);
    float4 o = make_float4(v.x * inv, v.y * inv, v.z * inv, v.w * inv);
    ((float4*)(qn + (size_t)row * D))[lane] = o;
}

// ---------------- warm rows: split-bf16 MFMA for mu/lv GEMM, kl, dec GEMM ----------------
// 64 rows/block, 4 waves, wave w owns rows 16w..16w+15 (all 256 output cols).
// MFMA 16x16x32 bf16; A-frag: lane holds X[rowbase+(lane&15)][ks*32+(lane>>4)*8+e]
// C/D: col = lane&15, row = (lane>>4)*4 + reg  [verified layout]
__global__ __launch_bounds__(256) void k_warm(const float* __restrict__ x,
        const unsigned short* __restrict__ wcat_h, const unsigned short* __restrict__ wcat_l,
        const unsigned short* __restrict__ wdec_h, const unsigned short* __restrict__ wdec_l,
        const float* __restrict__ bmu, const float* __restrict__ blv,
        const float* __restrict__ bdec,
        const int* __restrict__ warm_idx, const int* cnt,
        float* __restrict__ outF, float* klacc) {
    __shared__ __align__(16) unsigned short SM[2 * 64 * XPAD];  // 67584 B
    __shared__ float klbuf[4];
    unsigned short* XH = SM;
    unsigned short* XL = SM + 64 * XPAD;
    int nw = cnt[0];
    int base = blockIdx.x * 64;
    if (base >= nw) return;
    int m = min(64, nw - base);
    int tid = threadIdx.x;
    // stage gathered warm rows as hi/lo bf16
    for (int i = tid; i < 64 * 64; i += 256) {
        int r = i >> 6, c4 = i & 63;
        float4 v = make_float4(0.f, 0.f, 0.f, 0.f);
        if (r < m) v = ((const float4*)(x + (size_t)warm_idx[base + r] * D))[c4];
        unsigned short h0, h1, h2, h3, l0, l1, l2, l3;
        split2(v.x, h0, l0); split2(v.y, h1, l1); split2(v.z, h2, l2); split2(v.w, h3, l3);
        *(ushort4*)&XH[r * XPAD + c4 * 4] = make_ushort4(h0, h1, h2, h3);
        *(ushort4*)&XL[r * XPAD + c4 * 4] = make_ushort4(l0, l1, l2, l3);
    }
    __syncthreads();

    int w = tid >> 6, lane = tid & 63;
    int lm = lane & 15, lk = (lane >> 4) * 8;
    int rowbase = w * 16;
    f32x4 zero; zero[0] = 0.f; zero[1] = 0.f; zero[2] = 0.f; zero[3] = 0.f;

    // ---- GEMM1: [16 rows] x Wcat^T -> mu (frags 0..7) | lv (frags 8..15) ----
    f32x4 acc[16];
    #pragma unroll
    for (int n = 0; n < 16; ++n) acc[n] = zero;
    const unsigned short* ah_p = &XH[(rowbase + lm) * XPAD];
    const unsigned short* al_p = &XL[(rowbase + lm) * XPAD];
    for (int ks = 0; ks < 8; ++ks) {
        int kk = ks * 32 + lk;
        short8v ah = *(const short8v*)&ah_p[kk];
        short8v al = *(const short8v*)&al_p[kk];
        #pragma unroll
        for (int n = 0; n < 16; ++n) {
            size_t roff = ((size_t)(n * 16 + lm) << 8) + kk;  // row-major [256][256]
            short8v bh = *(const short8v*)(wcat_h + roff);
            short8v bl = *(const short8v*)(wcat_l + roff);
            acc[n] = __builtin_amdgcn_mfma_f32_16x16x32_bf16(ah, bh, acc[n], 0, 0, 0);
            acc[n] = __builtin_amdgcn_mfma_f32_16x16x32_bf16(al, bh, acc[n], 0, 0, 0);
            acc[n] = __builtin_amdgcn_mfma_f32_16x16x32_bf16(ah, bl, acc[n], 0, 0, 0);
        }
    }

    // ---- bias + KL (in-register) ----
    float kll = 0.f;
    int r4 = (lane >> 4) * 4;
    #pragma unroll
    for (int n = 0; n < 8; ++n) {
        float bm = bmu[n * 16 + lm];
        float bl_ = blv[n * 16 + lm];
        #pragma unroll
        for (int rg = 0; rg < 4; ++rg) {
            float mu = acc[n][rg] + bm;
            float lv = acc[n + 8][rg] + bl_;
            acc[n][rg] = mu;
            int rl = rowbase + r4 + rg;
            if (rl < m) kll += -0.5f * (1.f + lv - mu * mu - __expf(lv));
        }
    }
    #pragma unroll
    for (int s = 32; s; s >>= 1) kll += __shfl_xor(kll, s, 64);
    if (lane == 0) klbuf[w] = kll;
    __syncthreads();   // all GEMM1 LDS reads done; safe to reuse SM
    if (tid == 0) atomicAdd(klacc, klbuf[0] + klbuf[1] + klbuf[2] + klbuf[3]);

    // ---- write mu hi/lo into reused LDS ----
    unsigned short* MUH = SM;
    unsigned short* MUL = SM + 64 * MPAD;
    #pragma unroll
    for (int n = 0; n < 8; ++n) {
        #pragma unroll
        for (int rg = 0; rg < 4; ++rg) {
            int rl = rowbase + r4 + rg;
            unsigned short h, l;
            split2(acc[n][rg], h, l);
            MUH[rl * MPAD + n * 16 + lm] = h;
            MUL[rl * MPAD + n * 16 + lm] = l;
        }
    }
    __syncthreads();

    // ---- GEMM2: dec[16 rows][256] = mu[16][128] @ Wdec^T ----
    f32x4 acc2[16];
    #pragma unroll
    for (int n = 0; n < 16; ++n) acc2[n] = zero;
    const unsigned short* mh_p = &MUH[(rowbase + lm) * MPAD];
    const unsigned short* ml_p = &MUL[(rowbase + lm) * MPAD];
    for (int ks = 0; ks < 4; ++ks) {
        int kk = ks * 32 + lk;
        short8v ah = *(const short8v*)&mh_p[kk];
        short8v al = *(const short8v*)&ml_p[kk];
        #pragma unroll
        for (int n = 0; n < 16; ++n) {
            size_t roff = (size_t)(n * 16 + lm) * WDIM + kk;  // row-major [256][128]
            short8v bh = *(const short8v*)(wdec_h + roff);
            short8v bl = *(const short8v*)(wdec_l + roff);
            acc2[n] = __builtin_amdgcn_mfma_f32_16x16x32_bf16(ah, bh, acc2[n], 0, 0, 0);
            acc2[n] = __builtin_amdgcn_mfma_f32_16x16x32_bf16(al, bh, acc2[n], 0, 0, 0);
            acc2[n] = __builtin_amdgcn_mfma_f32_16x16x32_bf16(ah, bl, acc2[n], 0, 0, 0);
        }
    }

    // ---- scatter-store dec to warm rows ----
    int gidx[4];
    #pragma unroll
    for (int rg = 0; rg < 4; ++rg) {
        int rl = rowbase + r4 + rg;
        gidx[rg] = (rl < m) ? warm_idx[base + rl] : -1;
    }
    #pragma unroll
    for (int n = 0; n < 16; ++n) {
        float bd = bdec[n * 16 + lm];
        #pragma unroll
        for (int rg = 0; rg < 4; ++rg) {
            if (gidx[rg] >= 0)
                outF[(size_t)gidx[rg] * D + n * 16 + lm] = acc2[n][rg] + bd;
        }
    }
}

// ---------------- sim for cold rows ----------------
__global__ __launch_bounds__(256) void k_sim(const float* __restrict__ x,
                                             const float* __restrict__ qn,
                                             const int* __restrict__ cold_idx,
                                             const float* __restrict__ rowinv, const int* cnt,
                                             float* __restrict__ simC) {
    __shared__ float xs[64][256];
    int nc = cnt[1];
    int base = blockIdx.x * 64;
    if (base >= nc) return;
    int m = min(64, nc - base);
    int tid = threadIdx.x;
    for (int i = tid; i < 64 * 64; i += 256) {
        int r = i >> 6, c4 = i & 63;
        float4 v = make_float4(0.f, 0.f, 0.f, 0.f);
        if (r < m) v = ((const float4*)(x + (size_t)cold_idx[base + r] * D))[c4];
        *(float4*)&xs[r][c4 * 4] = v;
    }
    __syncthreads();
    int qg = tid & 15, rg = tid >> 4;
    int q0 = qg * 4, r0 = rg * 4;
    float acc[4][4] = {{0}};
    for (int k4 = 0; k4 < 64; ++k4) {
        float4 xv[4];
        #pragma unroll
        for (int i = 0; i < 4; ++i) xv[i] = *(const float4*)&xs[r0 + i][k4 * 4];
        #pragma unroll
        for (int j = 0; j < 4; ++j) {
            float4 qv = ((const float4*)(qn + (size_t)(q0 + j) * D))[k4];
            #pragma unroll
            for (int i = 0; i < 4; ++i)
                acc[i][j] += xv[i].x * qv.x + xv[i].y * qv.y + xv[i].z * qv.z + xv[i].w * qv.w;
        }
    }
    #pragma unroll
    for (int i = 0; i < 4; ++i) {
        int r = r0 + i;
        if (r < m) {
            float inv = rowinv[cold_idx[base + r]];
            #pragma unroll
            for (int j = 0; j < 4; ++j)
                simC[(size_t)(q0 + j) * nc + base + r] = acc[i][j] * inv;
        }
    }
}

// ---------------- top-k phase 1: per-(query,chunk) top-16 as u64 keys ----------------
__device__ __forceinline__ unsigned long long mkkey(float v, int gi) {
    unsigned int b = __float_as_uint(v);
    b = (b & 0x80000000u) ? ~b : (b | 0x80000000u);
    return ((unsigned long long)b << 32) | (unsigned int)(~gi);
}

#define CE(a, b) { unsigned long long _hi = (a) >= (b) ? (a) : (b); \
                   unsigned long long _lo = (a) >= (b) ? (b) : (a); \
                   (a) = _hi; (b) = _lo; }

__global__ __launch_bounds__(256) void k_top1(const float* __restrict__ simC,
                                              const int* __restrict__ cold_idx,
                                              const int* cnt, int Mmax,
                                              unsigned long long* __restrict__ cand) {
    __shared__ unsigned long long P0[256 * 17];
    __shared__ unsigned long long P1[128 * 17];
    int nc = cnt[1];
    int c = blockIdx.x, q = blockIdx.y;
    int base = c * CHUNK;
    if (base >= nc) return;
    int tid = threadIdx.x;
    const float* srow = simC + (size_t)q * nc;
    #define LOADK(s) ((base + tid + (s)*256 < nc) \
        ? mkkey(srow[base + tid + (s)*256], cold_idx[base + tid + (s)*256]) : 0ULL)
    unsigned long long k0 = LOADK(0), k1 = LOADK(1), k2 = LOADK(2), k3 = LOADK(3);
    unsigned long long k4 = LOADK(4), k5 = LOADK(5), k6 = LOADK(6), k7 = LOADK(7);
    #undef LOADK
    CE(k0,k1) CE(k2,k3) CE(k4,k5) CE(k6,k7)
    CE(k0,k2) CE(k1,k3) CE(k4,k6) CE(k5,k7)
    CE(k1,k2) CE(k5,k6)
    CE(k0,k4) CE(k1,k5) CE(k2,k6) CE(k3,k7)
    CE(k2,k4) CE(k3,k5)
    CE(k1,k2) CE(k3,k4) CE(k5,k6)
    unsigned long long* L = P0 + tid * 17;
    L[0]=k0; L[1]=k1; L[2]=k2; L[3]=k3; L[4]=k4; L[5]=k5; L[6]=k6; L[7]=k7;
    L[8]=0; L[9]=0; L[10]=0; L[11]=0; L[12]=0; L[13]=0; L[14]=0; L[15]=0;
    __syncthreads();
    unsigned long long* src = P0;
    unsigned long long* dst = P1;
    int nl = 256;
    while (nl > 1) {
        int half = nl >> 1;
        if (tid < half) {
            unsigned long long* A  = src + (2 * tid) * 17;
            unsigned long long* Bp = src + (2 * tid + 1) * 17;
            unsigned long long* O  = dst + tid * 17;
            int i = 0, j = 0;
            #pragma unroll
            for (int t = 0; t < 16; ++t) {
                unsigned long long ka = A[i], kb = Bp[j];
                bool ta = ka >= kb;
                O[t] = ta ? ka : kb;
                i += ta ? 1 : 0;
                j += ta ? 0 : 1;
            }
        }
        __syncthreads();
        unsigned long long* tmp = src; src = dst; dst = tmp;
        nl = half;
    }
    if (tid < 16) cand[((size_t)q * Mmax + c) * 16 + tid] = src[tid];
}

// ---------------- top-k phase 2: bitonic merge of candidates + gather ----------------
__global__ __launch_bounds__(256) void k_top2(const unsigned long long* __restrict__ cand,
                                              const int* cnt, int Mmax,
                                              const float* __restrict__ newF,
                                              float* __restrict__ outRetr,
                                              float* __restrict__ outIdx) {
    __shared__ unsigned long long K[C2];
    int q = blockIdx.x, tid = threadIdx.x;
    int nc = cnt[1];
    int M = (nc + CHUNK - 1) / CHUNK; if (M > Mmax) M = Mmax;
    int C = M * 16;
    for (int i = tid; i < C2; i += 256)
        K[i] = (i < C) ? cand[(size_t)q * Mmax * 16 + i] : 0ULL;
    __syncthreads();
    for (int kk = 2; kk <= C2; kk <<= 1) {
        for (int jj = kk >> 1; jj > 0; jj >>= 1) {
            for (int idx = tid; idx < C2; idx += 256) {
                int p = idx ^ jj;
                if (p > idx) {
                    bool dirDesc = ((idx & kk) == 0);
                    unsigned long long a = K[idx], b = K[p];
                    bool sw = dirDesc ? (a < b) : (a > b);
                    if (sw) { K[idx] = b; K[p] = a; }
                }
            }
            __syncthreads();
        }
    }
    if (tid < 16) {
        int gi = (int)(~(unsigned int)(K[tid] & 0xffffffffULL));
        outIdx[q * 16 + tid] = (float)gi;
    }
    for (int i = tid; i < 16 * D; i += 256) {
        int r = i >> 8, cc = i & 255;
        int gi = (int)(~(unsigned int)(K[r] & 0xffffffffULL));
        outRetr[(size_t)q * 16 * D + i] = newF[(size_t)gi * D + cc];
    }
}

// ---------------- kl finalize ----------------
__global__ void k_klfin(const int* cnt, float* outKl, int Wk) {
    float kl = ((const float*)cnt)[2];
    int nw = cnt[0]; if (nw < 1) nw = 1;
    *outKl = kl / ((float)nw * (float)Wk);
}

extern "C" void kernel_launch(void* const* d_in, const int* in_sizes, int n_in,
                              void* d_out, int out_size, void* d_ws, size_t ws_size,
                              hipStream_t stream) {
    (void)n_in; (void)out_size; (void)ws_size;
    const float* x    = (const float*)d_in[0];
    const int*   tier = (const int*)d_in[1];
    const float* qry  = (const float*)d_in[2];
    const float* Wmu  = (const float*)d_in[3];
    const float* bmu  = (const float*)d_in[4];
    const float* Wlv  = (const float*)d_in[5];
    const float* blv  = (const float*)d_in[6];
    const float* Wdec = (const float*)d_in[7];
    const float* bdec = (const float*)d_in[8];
    int N = in_sizes[0] / D;   // 200000
    int B = in_sizes[2] / D;   // 64
    int Wk = in_sizes[4];      // 128
    int Mmax = (N + CHUNK - 1) / CHUNK;  // 98

    float* outF    = (float*)d_out;
    float* outKl   = outF + (size_t)N * D;
    float* outRetr = outKl + 1;
    float* outIdx  = outRetr + (size_t)B * 16 * D;

    char* ws = (char*)d_ws;
    int*   cnt      = (int*)ws;                       // [warm, cold, klacc(float)]
    int*   warm_idx = (int*)(ws + 256);
    int*   cold_idx = warm_idx + N;
    float* rowinv   = (float*)(cold_idx + N);
    float* qn       = rowinv + N;
    unsigned long long* cand = (unsigned long long*)(qn + (size_t)B * D); // 8-aligned
    unsigned short* wcat_h = (unsigned short*)(cand + (size_t)B * Mmax * 16);
    unsigned short* wcat_l = wcat_h + 256 * 256;
    unsigned short* wdec_h = wcat_l + 256 * 256;
    unsigned short* wdec_l = wdec_h + 256 * WDIM;
    float* simC     = (float*)(wdec_l + 256 * WDIM);

    k_init<<<1, 64, 0, stream>>>(cnt);
    k_wconv<<<384, 256, 0, stream>>>(Wmu, Wlv, Wdec, wcat_h, wcat_l, wdec_h, wdec_l);
    k_copy_norm<<<(N + 3) / 4, 256, 0, stream>>>(x, outF, rowinv, N);
    k_classify<<<(N + 255) / 256, 256, 0, stream>>>(tier, cnt, warm_idx, cold_idx, N);
    k_qnorm<<<(B + 3) / 4, 256, 0, stream>>>(qry, qn, B);
    k_warm<<<(N + 63) / 64, 256, 0, stream>>>(x, wcat_h, wcat_l, wdec_h, wdec_l,
                                              bmu, blv, bdec, warm_idx, cnt,
                                              outF, (float*)cnt + 2);
    k_sim<<<(N + 63) / 64, 256, 0, stream>>>(x, qn, cold_idx, rowinv, cnt, simC);
    k_top1<<<dim3(Mmax, B), 256, 0, stream>>>(simC, cold_idx, cnt, Mmax, cand);
    k_top2<<<B, 256, 0, stream>>>(cand, cnt, Mmax, outF, outRetr, outIdx);
    k_klfin<<<1, 1, 0, stream>>>(cnt, outKl, Wk);
}

// Round 2
// 845.902 us; speedup vs baseline: 1.6589x; 1.1939x over previous
//
#include <hip/hip_runtime.h>
#include <math.h>

#define D 256
#define WDIM 128
#define EPSN 1e-10f
#define CHUNK 2048
#define C2 2048

typedef __attribute__((ext_vector_type(8))) short short8v;
typedef __attribute__((ext_vector_type(4))) float f32x4;

#define XPAD 264   // 256 + 8 bf16 pad -> row stride 528B = 33*16
#define MPAD 136   // 128 + 8 bf16 pad -> row stride 272B = 17*16

// ---- fp32 -> bf16 hi/lo split (RNE both): dropped lo*lo term ~2^-18 rel ----
__device__ __forceinline__ unsigned short bf16_rne(float f) {
    unsigned u = __float_as_uint(f);
    u += 0x7fffu + ((u >> 16) & 1u);
    return (unsigned short)(u >> 16);
}
__device__ __forceinline__ float bf16_tof(unsigned short h) {
    return __uint_as_float(((unsigned)h) << 16);
}
__device__ __forceinline__ void split2(float f, unsigned short& h, unsigned short& l) {
    h = bf16_rne(f);
    l = bf16_rne(f - bf16_tof(h));
}

// ---------------- init: zero counters ----------------
__global__ void k_init(int* cnt) {
    if (threadIdx.x == 0) { cnt[0] = 0; cnt[1] = 0; ((float*)cnt)[2] = 0.0f; }
}

// ---------------- weight conversion -> bf16 hi/lo, PACKED in MFMA frag order ----
// wcat packed: p = ((frag*8 + ks)*64 + lane)*8 + e
//   maps to wcat[row = frag*16 + (lane&15)][k = ks*32 + (lane>>4)*8 + e]
// wdec packed: p = ((frag*4 + ks)*64 + lane)*8 + e
//   maps to Wdec[row = frag*16 + (lane&15)][k = ks*32 + (lane>>4)*8 + e]
__global__ __launch_bounds__(256) void k_wconv(const float* __restrict__ Wmu,
                                               const float* __restrict__ Wlv,
                                               const float* __restrict__ Wdec,
                                               unsigned short* __restrict__ wcat_h,
                                               unsigned short* __restrict__ wcat_l,
                                               unsigned short* __restrict__ wdec_h,
                                               unsigned short* __restrict__ wdec_l) {
    int i = blockIdx.x * 256 + threadIdx.x;
    if (i < 65536) {                       // 256 frag-rows x 256 k
        int e = i & 7, lane = (i >> 3) & 63, ks = (i >> 9) & 7, n = i >> 12;
        int row = n * 16 + (lane & 15);
        int k = ks * 32 + ((lane >> 4) << 3) + e;
        float v = (row < 128) ? Wmu[row * 256 + k] : Wlv[(row - 128) * 256 + k];
        unsigned short h, l; split2(v, h, l);
        wcat_h[i] = h; wcat_l[i] = l;
    } else if (i < 98304) {                // 256 frag-rows x 128 k
        int j = i - 65536;
        int e = j & 7, lane = (j >> 3) & 63, ks = (j >> 9) & 3, n = j >> 11;
        int row = n * 16 + (lane & 15);
        int k = ks * 32 + ((lane >> 4) << 3) + e;
        unsigned short h, l; split2(Wdec[row * 128 + k], h, l);
        wdec_h[j] = h; wdec_l[j] = l;
    }
}

// ---------------- copy x -> new_features, compute per-row inv-norm ----------------
__global__ __launch_bounds__(256) void k_copy_norm(const float* __restrict__ x,
                                                   float* __restrict__ outF,
                                                   float* __restrict__ rowinv, int N) {
    int wid = threadIdx.x >> 6, lane = threadIdx.x & 63;
    int row = blockIdx.x * 4 + wid;
    if (row >= N) return;
    float4 v = ((const float4*)(x + (size_t)row * D))[lane];
    ((float4*)(outF + (size_t)row * D))[lane] = v;
    float s = v.x * v.x + v.y * v.y + v.z * v.z + v.w * v.w;
    #pragma unroll
    for (int m = 32; m; m >>= 1) s += __shfl_xor(s, m, 64);
    if (lane == 0) rowinv[row] = 1.0f / (sqrtf(s) + EPSN);
}

// ---------------- classify tiers into compacted lists ----------------
__global__ __launch_bounds__(256) void k_classify(const int* __restrict__ tiers, int* cnt,
                                                  int* __restrict__ warm_idx,
                                                  int* __restrict__ cold_idx, int N) {
    int i = blockIdx.x * 256 + threadIdx.x;
    bool w = false, c = false;
    if (i < N) { int t = tiers[i]; w = (t == 1); c = (t == 2); }
    unsigned long long mw = __ballot(w);
    unsigned long long mc = __ballot(c);
    int lane = threadIdx.x & 63;
    unsigned long long ltmask = (lane == 0) ? 0ULL : (~0ULL >> (64 - lane));
    int pw = __popcll(mw & ltmask);
    int pc = __popcll(mc & ltmask);
    int cw = __popcll(mw), cc = __popcll(mc);
    int bw = 0, bc = 0;
    if (lane == 0) {
        if (cw) bw = atomicAdd(&cnt[0], cw);
        if (cc) bc = atomicAdd(&cnt[1], cc);
    }
    bw = __shfl(bw, 0, 64);
    bc = __shfl(bc, 0, 64);
    if (w) warm_idx[bw + pw] = i;
    if (c) cold_idx[bc + pc] = i;
}

// ---------------- normalize queries ----------------
__global__ __launch_bounds__(256) void k_qnorm(const float* __restrict__ q,
                                               float* __restrict__ qn, int B) {
    int wid = threadIdx.x >> 6, lane = threadIdx.x & 63;
    int row = blockIdx.x * 4 + wid;
    if (row >= B) return;
    float4 v = ((const float4*)(q + (size_t)row * D))[lane];
    float s = v.x * v.x + v.y * v.y + v.z * v.z + v.w * v.w;
    #pragma unroll
    for (int m = 32; m; m >>= 1) s += __shfl_xor(s, m, 64);
    float inv = 1.0f / (sqrtf(s) + EPSN);
    float4 o = make_float4(v.x * inv, v.y * inv, v.z * inv, v.w * inv);
    ((float4*)(qn + (size_t)row * D))[lane] = o;
}

// ---------------- warm rows: split-bf16 MFMA, wave = 4 row-tiles x 4 col-frags ----
// Block: 64 rows, 4 waves. GEMM1 frags for wave w: {w, w+4, w+8, w+12}
//   -> mu frags (j=0,1) pair with lv frags (j=2,3) at the same lv column.
// GEMM2 frags for wave w: {4w, 4w+1, 4w+2, 4w+3}.
// MFMA 16x16x32 bf16. A-frag: lane holds A[tile*16+(lane&15)][ks*32+(lane>>4)*8+e].
// C/D: col = lane&15, row = (lane>>4)*4 + reg.
__global__ __launch_bounds__(256) void k_warm(const float* __restrict__ x,
        const unsigned short* __restrict__ wcat_h, const unsigned short* __restrict__ wcat_l,
        const unsigned short* __restrict__ wdec_h, const unsigned short* __restrict__ wdec_l,
        const float* __restrict__ bmu, const float* __restrict__ blv,
        const float* __restrict__ bdec,
        const int* __restrict__ warm_idx, const int* cnt,
        float* __restrict__ outF, float* klacc) {
    __shared__ __align__(16) unsigned short SM[2 * 64 * XPAD];  // 67584 B
    __shared__ float klbuf[4];
    __shared__ int widx[64];
    unsigned short* XH = SM;
    unsigned short* XL = SM + 64 * XPAD;
    int nw = cnt[0];
    int base = blockIdx.x * 64;
    if (base >= nw) return;
    int m = min(64, nw - base);
    int tid = threadIdx.x;
    if (tid < 64) widx[tid] = (tid < m) ? warm_idx[base + tid] : -1;
    // stage gathered warm rows as hi/lo bf16
    for (int i = tid; i < 64 * 64; i += 256) {
        int r = i >> 6, c4 = i & 63;
        float4 v = make_float4(0.f, 0.f, 0.f, 0.f);
        if (r < m) v = ((const float4*)(x + (size_t)warm_idx[base + r] * D))[c4];
        unsigned short h0, h1, h2, h3, l0, l1, l2, l3;
        split2(v.x, h0, l0); split2(v.y, h1, l1); split2(v.z, h2, l2); split2(v.w, h3, l3);
        *(ushort4*)&XH[r * XPAD + c4 * 4] = make_ushort4(h0, h1, h2, h3);
        *(ushort4*)&XL[r * XPAD + c4 * 4] = make_ushort4(l0, l1, l2, l3);
    }
    __syncthreads();

    int w = tid >> 6, lane = tid & 63;
    int lm = lane & 15, hi = lane >> 4;
    int lk = hi * 8, r4 = hi * 4;
    f32x4 zero; zero[0] = 0.f; zero[1] = 0.f; zero[2] = 0.f; zero[3] = 0.f;

    // ---- GEMM1: 64 rows x 64 cols per wave over K=256 ----
    f32x4 acc[4][4];
    #pragma unroll
    for (int t = 0; t < 4; ++t)
        #pragma unroll
        for (int j = 0; j < 4; ++j) acc[t][j] = zero;
    for (int ks = 0; ks < 8; ++ks) {
        int kk = ks * 32 + lk;
        short8v ah[4], al[4];
        #pragma unroll
        for (int t = 0; t < 4; ++t) {
            ah[t] = *(const short8v*)&XH[(t * 16 + lm) * XPAD + kk];
            al[t] = *(const short8v*)&XL[(t * 16 + lm) * XPAD + kk];
        }
        #pragma unroll
        for (int j = 0; j < 4; ++j) {
            int fn = w + 4 * j;
            short8v bh = ((const short8v*)wcat_h)[(fn * 8 + ks) * 64 + lane];
            short8v bl = ((const short8v*)wcat_l)[(fn * 8 + ks) * 64 + lane];
            #pragma unroll
            for (int t = 0; t < 4; ++t) {
                acc[t][j] = __builtin_amdgcn_mfma_f32_16x16x32_bf16(ah[t], bh, acc[t][j], 0, 0, 0);
                acc[t][j] = __builtin_amdgcn_mfma_f32_16x16x32_bf16(al[t], bh, acc[t][j], 0, 0, 0);
                acc[t][j] = __builtin_amdgcn_mfma_f32_16x16x32_bf16(ah[t], bl, acc[t][j], 0, 0, 0);
            }
        }
    }

    // ---- bias + KL (in-register; j and j+2 are the paired mu/lv frags) ----
    float kll = 0.f;
    #pragma unroll
    for (int j = 0; j < 2; ++j) {
        int fn = w + 4 * j;
        float bm = bmu[fn * 16 + lm];
        float bv = blv[fn * 16 + lm];
        #pragma unroll
        for (int t = 0; t < 4; ++t) {
            #pragma unroll
            for (int rg = 0; rg < 4; ++rg) {
                float mu = acc[t][j][rg] + bm;
                float lv = acc[t][j + 2][rg] + bv;
                acc[t][j][rg] = mu;
                int rl = t * 16 + r4 + rg;
                if (rl < m) kll += -0.5f * (1.f + lv - mu * mu - __expf(lv));
            }
        }
    }
    #pragma unroll
    for (int s = 32; s; s >>= 1) kll += __shfl_xor(kll, s, 64);
    if (lane == 0) klbuf[w] = kll;
    __syncthreads();   // all GEMM1 LDS reads done; safe to reuse SM
    if (tid == 0) atomicAdd(klacc, klbuf[0] + klbuf[1] + klbuf[2] + klbuf[3]);

    // ---- write mu hi/lo into reused LDS (wave w owns mu cols of frags w, w+4) ----
    unsigned short* MUH = SM;
    unsigned short* MUL = SM + 64 * MPAD;
    #pragma unroll
    for (int j = 0; j < 2; ++j) {
        int fn = w + 4 * j;
        int col = fn * 16 + lm;
        #pragma unroll
        for (int t = 0; t < 4; ++t) {
            #pragma unroll
            for (int rg = 0; rg < 4; ++rg) {
                int rl = t * 16 + r4 + rg;
                unsigned short h, l;
                split2(acc[t][j][rg], h, l);
                MUH[rl * MPAD + col] = h;
                MUL[rl * MPAD + col] = l;
            }
        }
    }
    __syncthreads();

    // ---- GEMM2: dec[64 rows][64 cols per wave] = mu[64][128] @ Wdec^T ----
    f32x4 acc2[4][4];
    #pragma unroll
    for (int t = 0; t < 4; ++t)
        #pragma unroll
        for (int j = 0; j < 4; ++j) acc2[t][j] = zero;
    for (int ks = 0; ks < 4; ++ks) {
        int kk = ks * 32 + lk;
        short8v ah[4], al[4];
        #pragma unroll
        for (int t = 0; t < 4; ++t) {
            ah[t] = *(const short8v*)&MUH[(t * 16 + lm) * MPAD + kk];
            al[t] = *(const short8v*)&MUL[(t * 16 + lm) * MPAD + kk];
        }
        #pragma unroll
        for (int j = 0; j < 4; ++j) {
            int fn = w * 4 + j;
            short8v bh = ((const short8v*)wdec_h)[(fn * 4 + ks) * 64 + lane];
            short8v bl = ((const short8v*)wdec_l)[(fn * 4 + ks) * 64 + lane];
            #pragma unroll
            for (int t = 0; t < 4; ++t) {
                acc2[t][j] = __builtin_amdgcn_mfma_f32_16x16x32_bf16(ah[t], bh, acc2[t][j], 0, 0, 0);
                acc2[t][j] = __builtin_amdgcn_mfma_f32_16x16x32_bf16(al[t], bh, acc2[t][j], 0, 0, 0);
                acc2[t][j] = __builtin_amdgcn_mfma_f32_16x16x32_bf16(ah[t], bl, acc2[t][j], 0, 0, 0);
            }
        }
    }

    // ---- scatter-store dec to warm rows ----
    #pragma unroll
    for (int j = 0; j < 4; ++j) {
        int fn = w * 4 + j;
        int col = fn * 16 + lm;
        float bd = bdec[col];
        #pragma unroll
        for (int t = 0; t < 4; ++t) {
            #pragma unroll
            for (int rg = 0; rg < 4; ++rg) {
                int rl = t * 16 + r4 + rg;
                int gi = widx[rl];
                if (gi >= 0)
                    outF[(size_t)gi * D + col] = acc2[t][j][rg] + bd;
            }
        }
    }
}

// ---------------- sim for cold rows ----------------
__global__ __launch_bounds__(256) void k_sim(const float* __restrict__ x,
                                             const float* __restrict__ qn,
                                             const int* __restrict__ cold_idx,
                                             const float* __restrict__ rowinv, const int* cnt,
                                             float* __restrict__ simC) {
    __shared__ float xs[64][256];
    int nc = cnt[1];
    int base = blockIdx.x * 64;
    if (base >= nc) return;
    int m = min(64, nc - base);
    int tid = threadIdx.x;
    for (int i = tid; i < 64 * 64; i += 256) {
        int r = i >> 6, c4 = i & 63;
        float4 v = make_float4(0.f, 0.f, 0.f, 0.f);
        if (r < m) v = ((const float4*)(x + (size_t)cold_idx[base + r] * D))[c4];
        *(float4*)&xs[r][c4 * 4] = v;
    }
    __syncthreads();
    int qg = tid & 15, rg = tid >> 4;
    int q0 = qg * 4, r0 = rg * 4;
    float acc[4][4] = {{0}};
    for (int k4 = 0; k4 < 64; ++k4) {
        float4 xv[4];
        #pragma unroll
        for (int i = 0; i < 4; ++i) xv[i] = *(const float4*)&xs[r0 + i][k4 * 4];
        #pragma unroll
        for (int j = 0; j < 4; ++j) {
            float4 qv = ((const float4*)(qn + (size_t)(q0 + j) * D))[k4];
            #pragma unroll
            for (int i = 0; i < 4; ++i)
                acc[i][j] += xv[i].x * qv.x + xv[i].y * qv.y + xv[i].z * qv.z + xv[i].w * qv.w;
        }
    }
    #pragma unroll
    for (int i = 0; i < 4; ++i) {
        int r = r0 + i;
        if (r < m) {
            float inv = rowinv[cold_idx[base + r]];
            #pragma unroll
            for (int j = 0; j < 4; ++j)
                simC[(size_t)(q0 + j) * nc + base + r] = acc[i][j] * inv;
        }
    }
}

// ---------------- top-k phase 1: per-(query,chunk) top-16 as u64 keys ----------------
__device__ __forceinline__ unsigned long long mkkey(float v, int gi) {
    unsigned int b = __float_as_uint(v);
    b = (b & 0x80000000u) ? ~b : (b | 0x80000000u);
    return ((unsigned long long)b << 32) | (unsigned int)(~gi);
}

#define CE(a, b) { unsigned long long _hi = (a) >= (b) ? (a) : (b); \
                   unsigned long long _lo = (a) >= (b) ? (b) : (a); \
                   (a) = _hi; (b) = _lo; }

__global__ __launch_bounds__(256) void k_top1(const float* __restrict__ simC,
                                              const int* __restrict__ cold_idx,
                                              const int* cnt, int Mmax,
                                              unsigned long long* __restrict__ cand) {
    __shared__ unsigned long long P0[256 * 17];
    __shared__ unsigned long long P1[128 * 17];
    int nc = cnt[1];
    int c = blockIdx.x, q = blockIdx.y;
    int base = c * CHUNK;
    if (base >= nc) return;
    int tid = threadIdx.x;
    const float* srow = simC + (size_t)q * nc;
    #define LOADK(s) ((base + tid + (s)*256 < nc) \
        ? mkkey(srow[base + tid + (s)*256], cold_idx[base + tid + (s)*256]) : 0ULL)
    unsigned long long k0 = LOADK(0), k1 = LOADK(1), k2 = LOADK(2), k3 = LOADK(3);
    unsigned long long k4 = LOADK(4), k5 = LOADK(5), k6 = LOADK(6), k7 = LOADK(7);
    #undef LOADK
    CE(k0,k1) CE(k2,k3) CE(k4,k5) CE(k6,k7)
    CE(k0,k2) CE(k1,k3) CE(k4,k6) CE(k5,k7)
    CE(k1,k2) CE(k5,k6)
    CE(k0,k4) CE(k1,k5) CE(k2,k6) CE(k3,k7)
    CE(k2,k4) CE(k3,k5)
    CE(k1,k2) CE(k3,k4) CE(k5,k6)
    unsigned long long* L = P0 + tid * 17;
    L[0]=k0; L[1]=k1; L[2]=k2; L[3]=k3; L[4]=k4; L[5]=k5; L[6]=k6; L[7]=k7;
    L[8]=0; L[9]=0; L[10]=0; L[11]=0; L[12]=0; L[13]=0; L[14]=0; L[15]=0;
    __syncthreads();
    unsigned long long* src = P0;
    unsigned long long* dst = P1;
    int nl = 256;
    while (nl > 1) {
        int half = nl >> 1;
        if (tid < half) {
            unsigned long long* A  = src + (2 * tid) * 17;
            unsigned long long* Bp = src + (2 * tid + 1) * 17;
            unsigned long long* O  = dst + tid * 17;
            int i = 0, j = 0;
            #pragma unroll
            for (int t = 0; t < 16; ++t) {
                unsigned long long ka = A[i], kb = Bp[j];
                bool ta = ka >= kb;
                O[t] = ta ? ka : kb;
                i += ta ? 1 : 0;
                j += ta ? 0 : 1;
            }
        }
        __syncthreads();
        unsigned long long* tmp = src; src = dst; dst = tmp;
        nl = half;
    }
    if (tid < 16) cand[((size_t)q * Mmax + c) * 16 + tid] = src[tid];
}

// ---------------- top-k phase 2: bitonic merge of candidates + gather ----------------
__global__ __launch_bounds__(256) void k_top2(const unsigned long long* __restrict__ cand,
                                              const int* cnt, int Mmax,
                                              const float* __restrict__ newF,
                                              float* __restrict__ outRetr,
                                              float* __restrict__ outIdx) {
    __shared__ unsigned long long K[C2];
    int q = blockIdx.x, tid = threadIdx.x;
    int nc = cnt[1];
    int M = (nc + CHUNK - 1) / CHUNK; if (M > Mmax) M = Mmax;
    int C = M * 16;
    for (int i = tid; i < C2; i += 256)
        K[i] = (i < C) ? cand[(size_t)q * Mmax * 16 + i] : 0ULL;
    __syncthreads();
    for (int kk = 2; kk <= C2; kk <<= 1) {
        for (int jj = kk >> 1; jj > 0; jj >>= 1) {
            for (int idx = tid; idx < C2; idx += 256) {
                int p = idx ^ jj;
                if (p > idx) {
                    bool dirDesc = ((idx & kk) == 0);
                    unsigned long long a = K[idx], b = K[p];
                    bool sw = dirDesc ? (a < b) : (a > b);
                    if (sw) { K[idx] = b; K[p] = a; }
                }
            }
            __syncthreads();
        }
    }
    if (tid < 16) {
        int gi = (int)(~(unsigned int)(K[tid] & 0xffffffffULL));
        outIdx[q * 16 + tid] = (float)gi;
    }
    for (int i = tid; i < 16 * D; i += 256) {
        int r = i >> 8, cc = i & 255;
        int gi = (int)(~(unsigned int)(K[r] & 0xffffffffULL));
        outRetr[(size_t)q * 16 * D + i] = newF[(size_t)gi * D + cc];
    }
}

// ---------------- kl finalize ----------------
__global__ void k_klfin(const int* cnt, float* outKl, int Wk) {
    float kl = ((const float*)cnt)[2];
    int nw = cnt[0]; if (nw < 1) nw = 1;
    *outKl = kl / ((float)nw * (float)Wk);
}

extern "C" void kernel_launch(void* const* d_in, const int* in_sizes, int n_in,
                              void* d_out, int out_size, void* d_ws, size_t ws_size,
                              hipStream_t stream) {
    (void)n_in; (void)out_size; (void)ws_size;
    const float* x    = (const float*)d_in[0];
    const int*   tier = (const int*)d_in[1];
    const float* qry  = (const float*)d_in[2];
    const float* Wmu  = (const float*)d_in[3];
    const float* bmu  = (const float*)d_in[4];
    const float* Wlv  = (const float*)d_in[5];
    const float* blv  = (const float*)d_in[6];
    const float* Wdec = (const float*)d_in[7];
    const float* bdec = (const float*)d_in[8];
    int N = in_sizes[0] / D;   // 200000
    int B = in_sizes[2] / D;   // 64
    int Wk = in_sizes[4];      // 128
    int Mmax = (N + CHUNK - 1) / CHUNK;  // 98

    float* outF    = (float*)d_out;
    float* outKl   = outF + (size_t)N * D;
    float* outRetr = outKl + 1;
    float* outIdx  = outRetr + (size_t)B * 16 * D;

    char* ws = (char*)d_ws;
    int*   cnt      = (int*)ws;                       // [warm, cold, klacc(float)]
    int*   warm_idx = (int*)(ws + 256);
    int*   cold_idx = warm_idx + N;
    float* rowinv   = (float*)(cold_idx + N);
    float* qn       = rowinv + N;
    unsigned long long* cand = (unsigned long long*)(qn + (size_t)B * D); // 8-aligned
    unsigned short* wcat_h = (unsigned short*)(cand + (size_t)B * Mmax * 16);
    unsigned short* wcat_l = wcat_h + 256 * 256;
    unsigned short* wdec_h = wcat_l + 256 * 256;
    unsigned short* wdec_l = wdec_h + 256 * WDIM;
    float* simC     = (float*)(wdec_l + 256 * WDIM);

    k_init<<<1, 64, 0, stream>>>(cnt);
    k_wconv<<<384, 256, 0, stream>>>(Wmu, Wlv, Wdec, wcat_h, wcat_l, wdec_h, wdec_l);
    k_copy_norm<<<(N + 3) / 4, 256, 0, stream>>>(x, outF, rowinv, N);
    k_classify<<<(N + 255) / 256, 256, 0, stream>>>(tier, cnt, warm_idx, cold_idx, N);
    k_qnorm<<<(B + 3) / 4, 256, 0, stream>>>(qry, qn, B);
    k_warm<<<(N + 63) / 64, 256, 0, stream>>>(x, wcat_h, wcat_l, wdec_h, wdec_l,
                                              bmu, blv, bdec, warm_idx, cnt,
                                              outF, (float*)cnt + 2);
    k_sim<<<(N + 63) / 64, 256, 0, stream>>>(x, qn, cold_idx, rowinv, cnt, simC);
    k_top1<<<dim3(Mmax, B), 256, 0, stream>>>(simC, cold_idx, cnt, Mmax, cand);
    k_top2<<<B, 256, 0, stream>>>(cand, cnt, Mmax, outF, outRetr, outIdx);
    k_klfin<<<1, 1, 0, stream>>>(cnt, outKl, Wk);
}